// Round 10
// baseline (6268.925 us; speedup 1.0000x reference)
//
#include <hip/hip_runtime.h>
#include <stdint.h>

#define TT 128
#define BB 128
#define NN 1024

// World model (verified bit-exact in R9):
//   tx: packed bf16 storage (runtime-probed each launch; probe also handles f32),
//   W : f32 storage, bf16-rounded values; b: f32; out: f32.
//   Reference recurrent sum: OpenBLAS sgemm kc=384 panels, sequential-k
//   single accumulator per panel, a = (P0 + P1) + P2.  With binary y all
//   products are exact, so this association is reproduced exactly.
//
// R19: the R10-R18 ledger (VMEM/CU 16x varied, DS/CU 5x varied, staging
// style varied; time constant; R10 with 2x per-CU traffic of R13 costs
// only +10%) kills every per-CU model. Survivor: per-XCD L2 bandwidth —
// all variants move the same ~10.6MB/XCD/step (every block re-reads its
// ~330 active rows each step). R19 cuts the TRAFFIC: block = 8-sample
// group x 64-col window (grid 16x16, 512 thr = 64 cols x 8 sample-waves);
// per step build the UNION active list over the 8 samples (~96% of rows
// vs 8x330 reads -> 0.37x L2 traffic), stage union rows ONCE into LDS
// (3-buffered 64-row chunks, 1 gload/wave/chunk, vmcnt(1), 1 barrier per
// chunk), each wave consumes only ITS sample's rows via a per-sample
// position list. Adds stay strictly ascending-k, one accumulator per
// panel, (P0+P1)+P2 -> bit-exact. Mask exchange = R13's verified
// tagged-cell protocol generalized to the 15 window-partners; blockIdx =
// r*16+g keeps all 16 group members on one XCD (idx%8 = g%8).

typedef unsigned short ushort8 __attribute__((ext_vector_type(8)));

__device__ __forceinline__ float bfbits2f(uint32_t lo16) {
  union { uint32_t i; float f; } c;
  c.i = lo16 << 16;
  return c.f;
}

__device__ __forceinline__ void gload_lds16(const void* g, void* l) {
  __builtin_amdgcn_global_load_lds(
      (const __attribute__((address_space(1))) uint32_t*)g,
      (__attribute__((address_space(3))) uint32_t*)l, 16, 0, 0);
}

// ---------------------------------------------------------------------------
// Kernel 0: in-place f32 transpose of W (tile-pair swap)  +  bf16 repack of
// W^T into ws  +  losslessness check (dirty flag set if any f32 word has
// nonzero low 16 bits — then the gather kernels use the f32 path).
// ---------------------------------------------------------------------------
__global__ __launch_bounds__(256) void w_transpose_repack(
    float* __restrict__ W, uint16_t* __restrict__ WtBf,
    uint32_t* __restrict__ dirty) {
  __shared__ float ta[32][33];
  __shared__ float tb[32][33];

  int rem = blockIdx.x;
  int I = 0;
  while (rem >= (32 - I)) { rem -= (32 - I); ++I; }
  const int J = I + rem;

  const int lx = threadIdx.x & 31;
  const int ly = threadIdx.x >> 5;  // 0..7
  uint32_t bad = 0;

  if (I == J) {
#pragma unroll
    for (int i = 0; i < 4; ++i)
      ta[ly + i * 8][lx] = W[(I * 32 + ly + i * 8) * NN + J * 32 + lx];
    __syncthreads();
#pragma unroll
    for (int i = 0; i < 4; ++i) {
      const int idx = (I * 32 + ly + i * 8) * NN + J * 32 + lx;
      const float v = ta[lx][ly + i * 8];
      const uint32_t bits = __float_as_uint(v);
      W[idx] = v;
      WtBf[idx] = (uint16_t)(bits >> 16);
      bad |= (bits & 0xFFFFu);
    }
  } else {
#pragma unroll
    for (int i = 0; i < 4; ++i) {
      ta[ly + i * 8][lx] = W[(I * 32 + ly + i * 8) * NN + J * 32 + lx];
      tb[ly + i * 8][lx] = W[(J * 32 + ly + i * 8) * NN + I * 32 + lx];
    }
    __syncthreads();
#pragma unroll
    for (int i = 0; i < 4; ++i) {
      const int idxA = (J * 32 + ly + i * 8) * NN + I * 32 + lx;
      const float va = ta[lx][ly + i * 8];
      const uint32_t bitsA = __float_as_uint(va);
      W[idxA] = va;
      WtBf[idxA] = (uint16_t)(bitsA >> 16);
      bad |= (bitsA & 0xFFFFu);

      const int idxB = (I * 32 + ly + i * 8) * NN + J * 32 + lx;
      const float vb = tb[lx][ly + i * 8];
      const uint32_t bitsB = __float_as_uint(vb);
      W[idxB] = vb;
      WtBf[idxB] = (uint16_t)(bitsB >> 16);
      bad |= (bitsB & 0xFFFFu);
    }
  }
  const unsigned long long bm = __ballot(bad != 0);
  if ((threadIdx.x & 63) == 0 && bm) atomicOr(dirty, 1u);
}

// ---------------------------------------------------------------------------
// Kernel 1a (primary): grouped LIF. Block bb: sample group g = bb&15
// (samples g*8..g*8+7), col window r = bb>>4 (neurons r*64..r*64+63).
// Wave sl = sample g*8+sl over the 64-col window. Union staging + per-
// sample ordered consume (see header).
// ---------------------------------------------------------------------------
__global__ __launch_bounds__(512) void lif_group(
    const void* __restrict__ tx_raw, const float* __restrict__ bias,
    const float* __restrict__ WtF32, const uint16_t* __restrict__ WtBf,
    const uint32_t* __restrict__ dirty,
    unsigned long long* __restrict__ gmask, float* __restrict__ out) {
  const int bb = blockIdx.x;
  const int g = bb & 15;           // sample group
  const int r = bb >> 4;           // col window (also k-chunk owned)
  const int tid = threadIdx.x;     // 0..511
  const int lane = tid & 63;       // col within window
  const int sl = tid >> 6;         // wave == sample lane 0..7
  const int b = g * 8 + sl;        // sample
  const int n = (r << 6) + lane;   // neuron index (== k-space position)

  __shared__ uint16_t sbuf[3][64][64] __attribute__((aligned(16)));  // 24KB
  __shared__ uint16_t ulst[1024] __attribute__((aligned(16)));       // union k list
  __shared__ uint16_t lst_s[8][1040] __attribute__((aligned(16)));   // 16.3KB
  __shared__ unsigned long long m8[8][16];   // [sample][k-chunk] masks
  __shared__ unsigned long long uch[16];     // union mask chunks
  __shared__ int sprobe;

  // ---- runtime tx-storage probe (bf16-packed vs f32), as verified in R9 ----
  if (tid == 0) sprobe = 0;
  __syncthreads();
  {
    const uint32_t* txw = (const uint32_t*)tx_raw;
    int local = 0;
#pragma unroll
    for (int i = 0; i < 2; ++i) {
      const uint32_t f = (txw[tid * 2 + i] >> 7) & 0xFFu;
      local += (f >= 0x74u && f < 0x81u) ? 1 : 0;
    }
    atomicAdd(&sprobe, local);
  }
  __syncthreads();
  const bool tx_is_bf16 = (sprobe > 512);    // of 1024 sampled words
  const bool w_bf = (*dirty == 0u);          // bf16 repack lossless?

  const uint16_t* __restrict__ txh = (const uint16_t*)tx_raw;
  const float* __restrict__ txf = (const float*)tx_raw;
  const float bz = bias[n];
  const char* __restrict__ wbase = (const char*)WtBf;

  float v = 0.0f;   // membrane (REST = 0)
  int y = 0;        // previous spike

  for (int t = 0; t < TT; ++t) {
    const int slq = t & 3;  // mod-4 slot
    // ---- ballot: wave sl's 64 bits ARE sample b's window-r mask chunk ----
    const unsigned long long m = __ballot(y);
    if (lane == 0) m8[sl][r] = m;
    if (lane < 2) {
      const uint32_t word = lane ? (uint32_t)(m >> 32) : (uint32_t)m;
      const unsigned long long cell =
          ((unsigned long long)(t + 1) << 32) | (unsigned long long)word;
      __hip_atomic_store(&gmask[((size_t)bb * 4 + slq) * 16 + sl * 2 + lane],
                         cell, __ATOMIC_RELAXED, __HIP_MEMORY_SCOPE_AGENT);
    }

    // issue tx load early; consumed after the gather
    const int off = (t * BB + b) * NN + n;
    float xx;
    if (tx_is_bf16)
      xx = bfbits2f((uint32_t)__builtin_nontemporal_load(&txh[off]));
    else
      xx = __builtin_nontemporal_load(&txf[off]);

    __syncthreads();  // SYNC_A: own masks in LDS; prior step fully done
    if (tid < 240) {
      // read the 15 window-partners' cells (tagged, fenceless — R13 proto)
      const int rr0 = tid >> 4;                 // 0..14
      const int cw = tid & 15;                  // sample*2 + word
      const int rr = rr0 + (rr0 >= r ? 1 : 0);  // skip own window
      const int pb = (rr << 4) + g;             // partner block, same XCD
      const size_t ci = ((size_t)pb * 4 + slq) * 16 + cw;
      unsigned long long cell;
      while (((cell = __hip_atomic_load(&gmask[ci], __ATOMIC_RELAXED,
                                        __HIP_MEMORY_SCOPE_AGENT)) >>
              32) != (unsigned long long)(t + 1)) {
        __builtin_amdgcn_s_sleep(1);
      }
      ((uint32_t*)&m8[cw >> 1][rr])[cw & 1] = (uint32_t)cell;
    }
    __syncthreads();  // SYNC_B: all 8 samples' full masks in LDS
    if (tid < 16) {
      unsigned long long u = 0;
#pragma unroll
      for (int s = 0; s < 8; ++s) u |= m8[s][tid];
      uch[tid] = u;
    }
    __syncthreads();  // SYNC_B2: union chunks ready

    // ---- union list build (wave sl -> chunks 2sl,2sl+1) + running prefix --
    int U = 0;
    {
      int up = 0;
#pragma unroll
      for (int j = 0; j < 16; ++j) {
        const unsigned long long ub = uch[j];
        if ((j >> 1) == sl) {
          if ((ub >> lane) & 1ull) {
            const int below = __popcll(ub & ((1ull << lane) - 1ull));
            ulst[up + below] = (uint16_t)(j * 64 + lane);
          }
        }
        up += __popcll(ub);
      }
      U = up;
    }
    const int nch = (U + 63) >> 6;
    if (tid < nch * 64 - U) ulst[U + tid] = (uint16_t)NN;  // k=1024 -> zero row

    // ---- per-sample position list (wave sl, ascending k == ascending pos) --
    int ct = 0, c0s = 0, c01s = 0;
    {
      const unsigned long long lm = (1ull << lane) - 1ull;
      int up = 0;
#pragma unroll
      for (int j = 0; j < 16; ++j) {
        const unsigned long long bits = m8[sl][j];
        const unsigned long long ub = uch[j];
        if ((bits >> lane) & 1ull) {
          const int rank = ct + __popcll(bits & lm);
          lst_s[sl][rank] = (uint16_t)(up + __popcll(ub & lm));
        }
        ct += __popcll(bits);
        up += __popcll(ub);
        if (j == 5) c0s = ct;
        if (j == 11) c01s = ct;
      }
    }
    {
      const int pad = (-ct) & 7;  // stopper-pad to x8 (0xFFFF never consumed)
      if (lane < pad) lst_s[sl][ct + lane] = 0xFFFFu;
    }
    __syncthreads();  // SYNC_C: ulst complete (lst_s is wave-private)

    // ---- gather: staged union chunks, per-sample ordered consume ----------
    float P0 = 0.0f, P1 = 0.0f, P2 = 0.0f;
    if (w_bf) {
      const size_t gsub = ((size_t)r << 7) + (size_t)((lane & 7) << 4);
      const int lrow = lane >> 3;
      // stage chunk ch: wave sl stages union rows [ch*64+sl*8, +8) — one
      // gload: lane j sources row lst-index sl*8+(j>>3), bytes (j&7)*16 of
      // the 128B window slice; linear LDS dest = rows sl*8.. of sbuf[cb].
      auto stagec = [&](int ch) {
        const int kk = (int)ulst[ch * 64 + sl * 8 + lrow];
        const int cb = ch - (ch / 3) * 3;
        gload_lds16(wbase + ((size_t)kk << 11) + gsub, &sbuf[cb][sl * 8][0]);
      };
      if (nch > 0) stagec(0);
      if (nch > 1) stagec(1);

      int basei = 0;
      bool have = false;
      uint32_t p0 = 0, p1 = 0, p2 = 0, p3 = 0, p4 = 0, p5 = 0, p6 = 0, p7 = 0;
      for (int ch = 0; ch < nch; ++ch) {
        // own stage(ch) landed (ch+1 may stay in flight), then barrier:
        // all waves' slices of chunk ch are in LDS; all waves done with
        // the buffer stage(ch+2) will overwrite (consumed at iter ch-1).
        if (ch + 1 < nch)
          asm volatile("s_waitcnt vmcnt(1)\n\ts_barrier" ::: "memory");
        else
          asm volatile("s_waitcnt vmcnt(0)\n\ts_barrier" ::: "memory");
        if (ch + 2 < nch) stagec(ch + 2);

        const int chend = (ch + 1) * 64;
        for (;;) {
          if (!have) {
            if (basei >= ct) break;
            const ushort8 pw = *(const ushort8*)(&lst_s[sl][basei]);
            p0 = pw[0]; p1 = pw[1]; p2 = pw[2]; p3 = pw[3];
            p4 = pw[4]; p5 = pw[5]; p6 = pw[6]; p7 = pw[7];
            have = true;
          }
          // consume window entries with pos < chend, in order; mark with
          // 0xFFFF (same value as stoppers; real pos < 1024 never collides)
#define STEPU(u, pu)                                                        \
          if ((int)pu < chend) {                                            \
            const int bsel = (int)pu >> 6;                                  \
            const uint16_t wv_ =                                            \
                sbuf[bsel - (bsel / 3) * 3][(int)pu & 63][lane];            \
            const float f_ = bfbits2f((uint32_t)wv_);                       \
            const int ix = basei + u;                                       \
            if (ix < c0s) P0 += f_;                                         \
            else if (ix < c01s) P1 += f_;                                   \
            else P2 += f_;                                                  \
            pu = 0xFFFFu;                                                   \
          }
          STEPU(0, p0) STEPU(1, p1) STEPU(2, p2) STEPU(3, p3)
          STEPU(4, p4) STEPU(5, p5) STEPU(6, p6) STEPU(7, p7)
#undef STEPU
          if (p7 == 0xFFFFu) { basei += 8; have = false; }
          else break;  // rest of window belongs to later chunks
        }
      }
    } else {
      // f32 fallback (cold path): direct loads, same ordered association.
      for (int i2 = 0; i2 < ct; ++i2) {
        const int pos = (int)lst_s[sl][i2];
        const int kk = (int)ulst[pos];
        const float w = WtF32[(size_t)kk * NN + n];
        if (i2 < c0s) P0 += w;
        else if (i2 < c01s) P1 += w;
        else P2 += w;
      }
    }
    const float a = (P0 + P1) + P2;

    // ---- LIF update, reference op order, f32 ----
    const float xv = (xx + a) + bz;
    v = (y ? 0.0f : 0.5f * v) + xv;
    y = (v > 0.5f);

    __builtin_nontemporal_store(y ? 1.0f : 0.0f, &out[off]);
    // No end-of-step barrier: all step-t LDS reads/stage writes complete
    // before each wave's SYNC_A(t+1); list/mask rewrites happen after
    // SYNC_A/B/B2(t+1), by which time every wave finished step t.
  }
}

// ---------------------------------------------------------------------------
// Kernel 1b (fallback, R10-verified): per-sample LIF, 128 blocks x 1024 thr.
// Used only if ws_size cannot hold the mask exchange buffers.
// ---------------------------------------------------------------------------
__global__ __launch_bounds__(1024) void lif_persample(
    const void* __restrict__ tx_raw, const float* __restrict__ bias,
    const float* __restrict__ WtF32, const uint16_t* __restrict__ WtBf,
    const uint32_t* __restrict__ dirty, float* __restrict__ out) {
  const int b = blockIdx.x;
  const int tid = threadIdx.x;
  const int lane = tid & 63;
  const int wv = tid >> 6;

  __shared__ uint16_t lst[NN] __attribute__((aligned(16)));
  __shared__ int wcnt[16];
  __shared__ int sprobe;

  if (tid == 0) sprobe = 0;
  __syncthreads();
  {
    const uint32_t* txw = (const uint32_t*)tx_raw;
    int local = 0;
#pragma unroll
    for (int i = 0; i < 2; ++i) {
      const uint32_t f = (txw[tid * 2 + i] >> 7) & 0xFFu;
      local += (f >= 0x74u && f < 0x81u) ? 1 : 0;
    }
    atomicAdd(&sprobe, local);
  }
  __syncthreads();
  const bool tx_is_bf16 = (sprobe > 1024);
  const bool w_bf = (*dirty == 0u);

  const uint16_t* __restrict__ txh = (const uint16_t*)tx_raw;
  const float* __restrict__ txf = (const float*)tx_raw;
  const float bz = bias[tid];

  const int pidx = (wv < 6) ? 0 : ((wv < 12) ? 1 : 2);
  const int pw0 = (pidx == 0) ? 0 : ((pidx == 1) ? 6 : 12);

  const uint16_t* __restrict__ rowB = WtBf + tid;
  const float* __restrict__ rowF = WtF32 + tid;

  float v = 0.0f;
  int y = 0;

  auto gB = [&](int pbase, int cnt) -> float {
    float acc = 0.0f;
    for (int i = 0; i < cnt; i += 32) {
      const ushort8* lp = (const ushort8*)(lst + pbase + i);
      const ushort8 a0 = lp[0];
      const ushort8 a1 = lp[1];
      const ushort8 a2 = lp[2];
      const ushort8 a3 = lp[3];
      float wbuf[32];
#pragma unroll
      for (int u = 0; u < 8; ++u) {
        const int k = __builtin_amdgcn_readfirstlane((int)a0[u]);
        wbuf[u] = bfbits2f((uint32_t)rowB[k << 10]);
      }
#pragma unroll
      for (int u = 0; u < 8; ++u) {
        const int k = __builtin_amdgcn_readfirstlane((int)a1[u]);
        wbuf[8 + u] = bfbits2f((uint32_t)rowB[k << 10]);
      }
#pragma unroll
      for (int u = 0; u < 8; ++u) {
        const int k = __builtin_amdgcn_readfirstlane((int)a2[u]);
        wbuf[16 + u] = bfbits2f((uint32_t)rowB[k << 10]);
      }
#pragma unroll
      for (int u = 0; u < 8; ++u) {
        const int k = __builtin_amdgcn_readfirstlane((int)a3[u]);
        wbuf[24 + u] = bfbits2f((uint32_t)rowB[k << 10]);
      }
#pragma unroll
      for (int u = 0; u < 32; ++u) acc += wbuf[u];
    }
    return acc;
  };

  auto gF = [&](int s, int e) -> float {
    float acc = 0.0f;
    int i = s;
    for (; i + 8 <= e; i += 8) {
      float w[8];
#pragma unroll
      for (int u = 0; u < 8; ++u) {
        const int k = __builtin_amdgcn_readfirstlane((int)lst[i + u]);
        w[u] = rowF[k << 10];
      }
#pragma unroll
      for (int u = 0; u < 8; ++u) acc += w[u];
    }
    for (; i < e; ++i) {
      const int k = __builtin_amdgcn_readfirstlane((int)lst[i]);
      acc += rowF[k << 10];
    }
    return acc;
  };

  for (int t = 0; t < TT; ++t) {
    const unsigned long long m = __ballot(y);
    if (lane == 0) wcnt[wv] = __popcll(m);
    __syncthreads();
    int base = 0, c0 = 0, c1 = 0, c2 = 0;
#pragma unroll
    for (int w = 0; w < 16; ++w) {
      const int c = wcnt[w];
      c0 += (w < 6) ? c : 0;
      c1 += (w >= 6 && w < 12) ? c : 0;
      c2 += (w >= 12) ? c : 0;
      base += (w >= pw0 && w < wv) ? c : 0;
    }
    if (y) {
      const int below = __builtin_amdgcn_mbcnt_hi(
          (uint32_t)(m >> 32), __builtin_amdgcn_mbcnt_lo((uint32_t)m, 0));
      lst[pidx * 384 + base + below] = (uint16_t)tid;
    }
    if (tid < 96) {
      const int p = tid >> 5, jn = tid & 31;
      const int c = (p == 0) ? c0 : ((p == 1) ? c1 : c2);
      if (c + jn < ((c + 31) & ~31)) lst[p * 384 + c + jn] = (uint16_t)NN;
    }
    __syncthreads();

    float P0, P1, P2;
    if (w_bf) {
      P0 = gB(0, (c0 + 31) & ~31);
      P1 = gB(384, (c1 + 31) & ~31);
      P2 = gB(768, (c2 + 31) & ~31);
    } else {
      P0 = gF(0, c0);
      P1 = gF(384, 384 + c1);
      P2 = gF(768, 768 + c2);
    }
    const float a = (P0 + P1) + P2;

    const int off = (t * BB + b) * NN + tid;
    const float xx = tx_is_bf16
        ? bfbits2f((uint32_t)__builtin_nontemporal_load(&txh[off]))
        : __builtin_nontemporal_load(&txf[off]);
    const float xv = (xx + a) + bz;
    v = (y ? 0.0f : 0.5f * v) + xv;
    y = (v > 0.5f);

    __builtin_nontemporal_store(y ? 1.0f : 0.0f, &out[off]);
  }
}

extern "C" void kernel_launch(void* const* d_in, const int* in_sizes, int n_in,
                              void* d_out, int out_size, void* d_ws, size_t ws_size,
                              hipStream_t stream) {
  // Inputs by element count: tx = 128*128*1024 (bf16-packed),
  // W = 1024*1024 (f32, bf16-valued), b = 1024 (f32).
  const void* tx = nullptr;
  float* W = nullptr;
  const float* bs = nullptr;
  for (int i = 0; i < n_in; ++i) {
    if (in_sizes[i] == TT * BB * NN) tx = d_in[i];
    else if (in_sizes[i] == NN * NN) W = (float*)d_in[i];
    else if (in_sizes[i] == NN) bs = (const float*)d_in[i];
  }
  float* out = (float*)d_out;                     // [T, B, N] f32 spikes

  // Workspace layout:
  //   [0, 2MB)                bf16 W^T (1024 rows)
  //   [2MB, 2MB+2KB)          zero row (sentinel k=1024)
  //   @2MB+2048               dirty flag (u32)
  //   @2MB+4096               gmask: u64[256 blocks][4 slots][16 cells] = 128KB
  const size_t MB2 = 2u * 1024u * 1024u;
  uint16_t* WtBf = (uint16_t*)d_ws;
  uint16_t* zrow = WtBf + NN * NN;                // row index 1024
  uint32_t* dirty = (uint32_t*)((char*)d_ws + MB2 + 2048u);
  unsigned long long* gmask =
      (unsigned long long*)((char*)d_ws + MB2 + 4096u);
  const size_t GMASK_BYTES = 256u * 4u * 16u * 8u;  // 131072
  const size_t need = MB2 + 4096u + GMASK_BYTES;

  // ws is poisoned 0xAA each launch — clear dirty flag, sentinel row, cells.
  hipMemsetAsync(dirty, 0, sizeof(uint32_t), stream);
  hipMemsetAsync(zrow, 0, NN * sizeof(uint16_t), stream);

  w_transpose_repack<<<dim3(528), dim3(256), 0, stream>>>(W, WtBf, dirty);

  if (ws_size >= need) {
    hipMemsetAsync(gmask, 0, GMASK_BYTES, stream);
    lif_group<<<dim3(256), dim3(512), 0, stream>>>(tx, bs, W, WtBf, dirty,
                                                   gmask, out);
  } else {
    lif_persample<<<dim3(BB), dim3(1024), 0, stream>>>(tx, bs, W, WtBf, dirty,
                                                       out);
  }
}

// Round 11
// 1764.542 us; speedup vs baseline: 3.5527x; 3.5527x over previous
//
#include <hip/hip_runtime.h>
#include <stdint.h>

#define TT 128
#define BB 128
#define NN 1024

// World model (verified bit-exact in R9):
//   tx: packed bf16 storage (runtime-probed each launch; probe also handles f32),
//   W : f32 storage, bf16-rounded values; b: f32; out: f32.
//   Reference recurrent sum: OpenBLAS sgemm kc=384 panels, sequential-k
//   single accumulator per panel, a = (P0 + P1) + P2.  With binary y all
//   products are exact, so this association is reproduced exactly.
//
// R20: the R10-R18 ledger showed all variants move the SAME ~169k L2
// lines/XCD/step (time-invariant wall = L2 traffic). But the staged data
// is W — A CONSTANT. A block owning a fixed 64-col window of W^T needs
// 1024 rows x 128B = 128KB, which fits in LDS permanently. Stage ONCE
// before the t-loop; per-step W traffic through L2 -> ZERO.
//   - block = (8-sample group g)=bb&15 x (64-col window r)=bb>>4;
//     grid 256 = 1 block/CU, 512 thr = 8 sample-waves; group's 16
//     window-blocks share XCD g%8.
//   - prologue: 16 gload_lds16 per wave stage rows [sl*128,(sl+1)*128);
//     vmcnt(0) + barrier; sentinel row sbuf[1024]=0.
//   - per step: R19's 15-partner tagged-cell exchange (verified passing),
//     per-wave per-sample compact ascending-k list (panel bases {0,384,
//     768}, pad-to-8 with k=1024 -> zero row, +0.0f exact), consume =
//     ds_read_u16 sbuf[k][lane] + add (2-way bank alias = free), ONE
//     accumulator per panel, (P0+P1)+P2 -> bit-exact association.

typedef unsigned short ushort8 __attribute__((ext_vector_type(8)));

__device__ __forceinline__ float bfbits2f(uint32_t lo16) {
  union { uint32_t i; float f; } c;
  c.i = lo16 << 16;
  return c.f;
}

__device__ __forceinline__ void gload_lds16(const void* g, void* l) {
  __builtin_amdgcn_global_load_lds(
      (const __attribute__((address_space(1))) uint32_t*)g,
      (__attribute__((address_space(3))) uint32_t*)l, 16, 0, 0);
}

// ---------------------------------------------------------------------------
// Kernel 0: in-place f32 transpose of W (tile-pair swap)  +  bf16 repack of
// W^T into ws  +  losslessness check (dirty flag set if any f32 word has
// nonzero low 16 bits — then the gather kernels use the f32 path).
// ---------------------------------------------------------------------------
__global__ __launch_bounds__(256) void w_transpose_repack(
    float* __restrict__ W, uint16_t* __restrict__ WtBf,
    uint32_t* __restrict__ dirty) {
  __shared__ float ta[32][33];
  __shared__ float tb[32][33];

  int rem = blockIdx.x;
  int I = 0;
  while (rem >= (32 - I)) { rem -= (32 - I); ++I; }
  const int J = I + rem;

  const int lx = threadIdx.x & 31;
  const int ly = threadIdx.x >> 5;  // 0..7
  uint32_t bad = 0;

  if (I == J) {
#pragma unroll
    for (int i = 0; i < 4; ++i)
      ta[ly + i * 8][lx] = W[(I * 32 + ly + i * 8) * NN + J * 32 + lx];
    __syncthreads();
#pragma unroll
    for (int i = 0; i < 4; ++i) {
      const int idx = (I * 32 + ly + i * 8) * NN + J * 32 + lx;
      const float v = ta[lx][ly + i * 8];
      const uint32_t bits = __float_as_uint(v);
      W[idx] = v;
      WtBf[idx] = (uint16_t)(bits >> 16);
      bad |= (bits & 0xFFFFu);
    }
  } else {
#pragma unroll
    for (int i = 0; i < 4; ++i) {
      ta[ly + i * 8][lx] = W[(I * 32 + ly + i * 8) * NN + J * 32 + lx];
      tb[ly + i * 8][lx] = W[(J * 32 + ly + i * 8) * NN + I * 32 + lx];
    }
    __syncthreads();
#pragma unroll
    for (int i = 0; i < 4; ++i) {
      const int idxA = (J * 32 + ly + i * 8) * NN + I * 32 + lx;
      const float va = ta[lx][ly + i * 8];
      const uint32_t bitsA = __float_as_uint(va);
      W[idxA] = va;
      WtBf[idxA] = (uint16_t)(bitsA >> 16);
      bad |= (bitsA & 0xFFFFu);

      const int idxB = (I * 32 + ly + i * 8) * NN + J * 32 + lx;
      const float vb = tb[lx][ly + i * 8];
      const uint32_t bitsB = __float_as_uint(vb);
      W[idxB] = vb;
      WtBf[idxB] = (uint16_t)(bitsB >> 16);
      bad |= (bitsB & 0xFFFFu);
    }
  }
  const unsigned long long bm = __ballot(bad != 0);
  if ((threadIdx.x & 63) == 0 && bm) atomicOr(dirty, 1u);
}

// ---------------------------------------------------------------------------
// Kernel 1a (primary): grouped LIF with LDS-resident W window.
// Block bb: sample group g = bb&15 (samples g*8..g*8+7), col window
// r = bb>>4 (neurons r*64..r*64+63). Wave sl = sample g*8+sl.
// ---------------------------------------------------------------------------
__global__ __launch_bounds__(512) void lif_group(
    const void* __restrict__ tx_raw, const float* __restrict__ bias,
    const float* __restrict__ WtF32, const uint16_t* __restrict__ WtBf,
    const uint32_t* __restrict__ dirty,
    unsigned long long* __restrict__ gmask, float* __restrict__ out) {
  const int bb = blockIdx.x;
  const int g = bb & 15;           // sample group
  const int r = bb >> 4;           // col window
  const int tid = threadIdx.x;     // 0..511
  const int lane = tid & 63;       // col within window
  const int sl = tid >> 6;         // wave == sample lane 0..7
  const int b = g * 8 + sl;        // sample
  const int n = (r << 6) + lane;   // neuron index

  __shared__ uint16_t sbuf[1025][64] __attribute__((aligned(16)));  // 128KB+row
  __shared__ uint16_t lst_s[8][1032] __attribute__((aligned(16)));  // 16.1KB
  __shared__ unsigned long long m8[8][16];   // [sample][k-chunk] masks
  __shared__ int sprobe;

  // ---- runtime tx-storage probe (bf16-packed vs f32), as verified in R9 ----
  if (tid == 0) sprobe = 0;
  __syncthreads();
  {
    const uint32_t* txw = (const uint32_t*)tx_raw;
    int local = 0;
#pragma unroll
    for (int i = 0; i < 2; ++i) {
      const uint32_t f = (txw[tid * 2 + i] >> 7) & 0xFFu;
      local += (f >= 0x74u && f < 0x81u) ? 1 : 0;
    }
    atomicAdd(&sprobe, local);
  }
  __syncthreads();
  const bool tx_is_bf16 = (sprobe > 512);    // of 1024 sampled words
  const bool w_bf = (*dirty == 0u);          // bf16 repack lossless?

  const uint16_t* __restrict__ txh = (const uint16_t*)tx_raw;
  const float* __restrict__ txf = (const float*)tx_raw;
  const float bz = bias[n];

  // ---- one-time staging: this block's 64-col window of ALL 1024 rows ----
  if (w_bf) {
    const char* __restrict__ wb = (const char*)WtBf;
    const size_t gsub = ((size_t)r << 7) + (size_t)((lane & 7) << 4);
    const int lrow = lane >> 3;
#pragma unroll
    for (int i = 0; i < 16; ++i) {
      const int rb = (sl << 7) + (i << 3);  // rows rb..rb+7
      const int k = rb + lrow;
      gload_lds16(wb + ((size_t)k << 11) + gsub, &sbuf[rb][0]);
    }
    asm volatile("s_waitcnt vmcnt(0)" ::: "memory");
  }
  if (tid < 64) sbuf[1024][tid] = 0;  // sentinel row (k=1024 -> +0.0f)
  __syncthreads();

  float v = 0.0f;   // membrane (REST = 0)
  int y = 0;        // previous spike

  for (int t = 0; t < TT; ++t) {
    const int slq = t & 3;  // mod-4 slot
    // ---- ballot: wave sl's 64 bits ARE sample b's window-r mask chunk ----
    const unsigned long long m = __ballot(y);
    if (lane == 0) m8[sl][r] = m;
    if (lane < 2) {
      const uint32_t word = lane ? (uint32_t)(m >> 32) : (uint32_t)m;
      const unsigned long long cell =
          ((unsigned long long)(t + 1) << 32) | (unsigned long long)word;
      __hip_atomic_store(&gmask[((size_t)bb * 4 + slq) * 16 + sl * 2 + lane],
                         cell, __ATOMIC_RELAXED, __HIP_MEMORY_SCOPE_AGENT);
    }

    // issue tx load early; consumed after the gather
    const int off = (t * BB + b) * NN + n;
    float xx;
    if (tx_is_bf16)
      xx = bfbits2f((uint32_t)__builtin_nontemporal_load(&txh[off]));
    else
      xx = __builtin_nontemporal_load(&txf[off]);

    __syncthreads();  // SYNC_A: own masks in LDS; prior-step LDS reads done
    if (tid < 240) {
      // read the 15 window-partners' cells (tagged, fenceless — verified)
      const int rr0 = tid >> 4;                 // 0..14
      const int cw = tid & 15;                  // sample*2 + word
      const int rr = rr0 + (rr0 >= r ? 1 : 0);  // skip own window
      const int pb = (rr << 4) + g;             // partner block, same XCD
      const size_t ci = ((size_t)pb * 4 + slq) * 16 + cw;
      unsigned long long cell;
      while (((cell = __hip_atomic_load(&gmask[ci], __ATOMIC_RELAXED,
                                        __HIP_MEMORY_SCOPE_AGENT)) >>
              32) != (unsigned long long)(t + 1)) {
        __builtin_amdgcn_s_sleep(1);
      }
      ((uint32_t*)&m8[cw >> 1][rr])[cw & 1] = (uint32_t)cell;
    }
    __syncthreads();  // SYNC_B: all 8 samples' full masks in LDS

    // ---- per-wave list build for sample sl: ascending k, panel bases ----
    int ct0, ct1, ct2;
    {
      const unsigned long long lm = (1ull << lane) - 1ull;
      int pos = 0;
#pragma unroll
      for (int j = 0; j < 6; ++j) {
        const unsigned long long bits = m8[sl][j];
        if ((bits >> lane) & 1ull)
          lst_s[sl][pos + __popcll(bits & lm)] = (uint16_t)(j * 64 + lane);
        pos += __popcll(bits);
      }
      ct0 = pos;
      if (lane < (((ct0 + 7) & ~7) - ct0))
        lst_s[sl][ct0 + lane] = (uint16_t)1024;

      pos = 384;
#pragma unroll
      for (int j = 6; j < 12; ++j) {
        const unsigned long long bits = m8[sl][j];
        if ((bits >> lane) & 1ull)
          lst_s[sl][pos + __popcll(bits & lm)] = (uint16_t)(j * 64 + lane);
        pos += __popcll(bits);
      }
      ct1 = pos - 384;
      if (lane < (((ct1 + 7) & ~7) - ct1))
        lst_s[sl][384 + ct1 + lane] = (uint16_t)1024;

      pos = 768;
#pragma unroll
      for (int j = 12; j < 16; ++j) {
        const unsigned long long bits = m8[sl][j];
        if ((bits >> lane) & 1ull)
          lst_s[sl][pos + __popcll(bits & lm)] = (uint16_t)(j * 64 + lane);
        pos += __popcll(bits);
      }
      ct2 = pos - 768;
      if (lane < (((ct2 + 7) & ~7) - ct2))
        lst_s[sl][768 + ct2 + lane] = (uint16_t)1024;
    }
    // lst_s is wave-private; ds_writes land before own ds_reads (program
    // order + lgkmcnt); no barrier needed before consume.

    // ---- recurrent term: (P0 + P1) + P2, sequential k within panels ----
    float P0 = 0.0f, P1 = 0.0f, P2 = 0.0f;
    if (w_bf) {
      auto gP = [&](int base, int cnt, float& P) {
        for (int i = 0; i < cnt; i += 8) {
          const ushort8 ks = *(const ushort8*)(&lst_s[sl][base + i]);
#pragma unroll
          for (int u = 0; u < 8; ++u) {
            const int k = (int)ks[u];
            P += bfbits2f((uint32_t)sbuf[k][lane]);
          }
        }
      };
      gP(0, (ct0 + 7) & ~7, P0);
      gP(384, (ct1 + 7) & ~7, P1);
      gP(768, (ct2 + 7) & ~7, P2);
    } else {
      // f32 fallback (cold path): direct global loads, true counts.
      for (int i = 0; i < ct0; ++i) {
        const int k = (int)lst_s[sl][i];
        P0 += WtF32[(size_t)k * NN + n];
      }
      for (int i = 0; i < ct1; ++i) {
        const int k = (int)lst_s[sl][384 + i];
        P1 += WtF32[(size_t)k * NN + n];
      }
      for (int i = 0; i < ct2; ++i) {
        const int k = (int)lst_s[sl][768 + i];
        P2 += WtF32[(size_t)k * NN + n];
      }
    }
    const float a = (P0 + P1) + P2;

    // ---- LIF update, reference op order, f32 ----
    const float xv = (xx + a) + bz;
    v = (y ? 0.0f : 0.5f * v) + xv;
    y = (v > 0.5f);

    __builtin_nontemporal_store(y ? 1.0f : 0.0f, &out[off]);
    // No end-of-step barrier: each wave's step-t LDS reads precede its own
    // SYNC_A(t+1) (program order); m8/lst rewrites happen after SYNC_A/B.
  }
}

// ---------------------------------------------------------------------------
// Kernel 1b (fallback, R10-verified): per-sample LIF, 128 blocks x 1024 thr.
// Used only if ws_size cannot hold the mask exchange buffers.
// ---------------------------------------------------------------------------
__global__ __launch_bounds__(1024) void lif_persample(
    const void* __restrict__ tx_raw, const float* __restrict__ bias,
    const float* __restrict__ WtF32, const uint16_t* __restrict__ WtBf,
    const uint32_t* __restrict__ dirty, float* __restrict__ out) {
  const int b = blockIdx.x;
  const int tid = threadIdx.x;
  const int lane = tid & 63;
  const int wv = tid >> 6;

  __shared__ uint16_t lst[NN] __attribute__((aligned(16)));
  __shared__ int wcnt[16];
  __shared__ int sprobe;

  if (tid == 0) sprobe = 0;
  __syncthreads();
  {
    const uint32_t* txw = (const uint32_t*)tx_raw;
    int local = 0;
#pragma unroll
    for (int i = 0; i < 2; ++i) {
      const uint32_t f = (txw[tid * 2 + i] >> 7) & 0xFFu;
      local += (f >= 0x74u && f < 0x81u) ? 1 : 0;
    }
    atomicAdd(&sprobe, local);
  }
  __syncthreads();
  const bool tx_is_bf16 = (sprobe > 1024);
  const bool w_bf = (*dirty == 0u);

  const uint16_t* __restrict__ txh = (const uint16_t*)tx_raw;
  const float* __restrict__ txf = (const float*)tx_raw;
  const float bz = bias[tid];

  const int pidx = (wv < 6) ? 0 : ((wv < 12) ? 1 : 2);
  const int pw0 = (pidx == 0) ? 0 : ((pidx == 1) ? 6 : 12);

  const uint16_t* __restrict__ rowB = WtBf + tid;
  const float* __restrict__ rowF = WtF32 + tid;

  float v = 0.0f;
  int y = 0;

  auto gB = [&](int pbase, int cnt) -> float {
    float acc = 0.0f;
    for (int i = 0; i < cnt; i += 32) {
      const ushort8* lp = (const ushort8*)(lst + pbase + i);
      const ushort8 a0 = lp[0];
      const ushort8 a1 = lp[1];
      const ushort8 a2 = lp[2];
      const ushort8 a3 = lp[3];
      float wbuf[32];
#pragma unroll
      for (int u = 0; u < 8; ++u) {
        const int k = __builtin_amdgcn_readfirstlane((int)a0[u]);
        wbuf[u] = bfbits2f((uint32_t)rowB[k << 10]);
      }
#pragma unroll
      for (int u = 0; u < 8; ++u) {
        const int k = __builtin_amdgcn_readfirstlane((int)a1[u]);
        wbuf[8 + u] = bfbits2f((uint32_t)rowB[k << 10]);
      }
#pragma unroll
      for (int u = 0; u < 8; ++u) {
        const int k = __builtin_amdgcn_readfirstlane((int)a2[u]);
        wbuf[16 + u] = bfbits2f((uint32_t)rowB[k << 10]);
      }
#pragma unroll
      for (int u = 0; u < 8; ++u) {
        const int k = __builtin_amdgcn_readfirstlane((int)a3[u]);
        wbuf[24 + u] = bfbits2f((uint32_t)rowB[k << 10]);
      }
#pragma unroll
      for (int u = 0; u < 32; ++u) acc += wbuf[u];
    }
    return acc;
  };

  auto gF = [&](int s, int e) -> float {
    float acc = 0.0f;
    int i = s;
    for (; i + 8 <= e; i += 8) {
      float w[8];
#pragma unroll
      for (int u = 0; u < 8; ++u) {
        const int k = __builtin_amdgcn_readfirstlane((int)lst[i + u]);
        w[u] = rowF[k << 10];
      }
#pragma unroll
      for (int u = 0; u < 8; ++u) acc += w[u];
    }
    for (; i < e; ++i) {
      const int k = __builtin_amdgcn_readfirstlane((int)lst[i]);
      acc += rowF[k << 10];
    }
    return acc;
  };

  for (int t = 0; t < TT; ++t) {
    const unsigned long long m = __ballot(y);
    if (lane == 0) wcnt[wv] = __popcll(m);
    __syncthreads();
    int base = 0, c0 = 0, c1 = 0, c2 = 0;
#pragma unroll
    for (int w = 0; w < 16; ++w) {
      const int c = wcnt[w];
      c0 += (w < 6) ? c : 0;
      c1 += (w >= 6 && w < 12) ? c : 0;
      c2 += (w >= 12) ? c : 0;
      base += (w >= pw0 && w < wv) ? c : 0;
    }
    if (y) {
      const int below = __builtin_amdgcn_mbcnt_hi(
          (uint32_t)(m >> 32), __builtin_amdgcn_mbcnt_lo((uint32_t)m, 0));
      lst[pidx * 384 + base + below] = (uint16_t)tid;
    }
    if (tid < 96) {
      const int p = tid >> 5, jn = tid & 31;
      const int c = (p == 0) ? c0 : ((p == 1) ? c1 : c2);
      if (c + jn < ((c + 31) & ~31)) lst[p * 384 + c + jn] = (uint16_t)NN;
    }
    __syncthreads();

    float P0, P1, P2;
    if (w_bf) {
      P0 = gB(0, (c0 + 31) & ~31);
      P1 = gB(384, (c1 + 31) & ~31);
      P2 = gB(768, (c2 + 31) & ~31);
    } else {
      P0 = gF(0, c0);
      P1 = gF(384, 384 + c1);
      P2 = gF(768, 768 + c2);
    }
    const float a = (P0 + P1) + P2;

    const int off = (t * BB + b) * NN + tid;
    const float xx = tx_is_bf16
        ? bfbits2f((uint32_t)__builtin_nontemporal_load(&txh[off]))
        : __builtin_nontemporal_load(&txf[off]);
    const float xv = (xx + a) + bz;
    v = (y ? 0.0f : 0.5f * v) + xv;
    y = (v > 0.5f);

    __builtin_nontemporal_store(y ? 1.0f : 0.0f, &out[off]);
  }
}

extern "C" void kernel_launch(void* const* d_in, const int* in_sizes, int n_in,
                              void* d_out, int out_size, void* d_ws, size_t ws_size,
                              hipStream_t stream) {
  // Inputs by element count: tx = 128*128*1024 (bf16-packed),
  // W = 1024*1024 (f32, bf16-valued), b = 1024 (f32).
  const void* tx = nullptr;
  float* W = nullptr;
  const float* bs = nullptr;
  for (int i = 0; i < n_in; ++i) {
    if (in_sizes[i] == TT * BB * NN) tx = d_in[i];
    else if (in_sizes[i] == NN * NN) W = (float*)d_in[i];
    else if (in_sizes[i] == NN) bs = (const float*)d_in[i];
  }
  float* out = (float*)d_out;                     // [T, B, N] f32 spikes

  // Workspace layout:
  //   [0, 2MB)                bf16 W^T (1024 rows)
  //   [2MB, 2MB+2KB)          zero row (sentinel k=1024, fallback kernel)
  //   @2MB+2048               dirty flag (u32)
  //   @2MB+4096               gmask: u64[256 blocks][4 slots][16 cells] = 128KB
  const size_t MB2 = 2u * 1024u * 1024u;
  uint16_t* WtBf = (uint16_t*)d_ws;
  uint16_t* zrow = WtBf + NN * NN;                // row index 1024
  uint32_t* dirty = (uint32_t*)((char*)d_ws + MB2 + 2048u);
  unsigned long long* gmask =
      (unsigned long long*)((char*)d_ws + MB2 + 4096u);
  const size_t GMASK_BYTES = 256u * 4u * 16u * 8u;  // 131072
  const size_t need = MB2 + 4096u + GMASK_BYTES;

  // ws is poisoned 0xAA each launch — clear dirty flag, sentinel row, cells.
  hipMemsetAsync(dirty, 0, sizeof(uint32_t), stream);
  hipMemsetAsync(zrow, 0, NN * sizeof(uint16_t), stream);

  w_transpose_repack<<<dim3(528), dim3(256), 0, stream>>>(W, WtBf, dirty);

  if (ws_size >= need) {
    hipMemsetAsync(gmask, 0, GMASK_BYTES, stream);
    lif_group<<<dim3(256), dim3(512), 0, stream>>>(tx, bs, W, WtBf, dirty,
                                                   gmask, out);
  } else {
    lif_persample<<<dim3(BB), dim3(1024), 0, stream>>>(tx, bs, W, WtBf, dirty,
                                                       out);
  }
}